// Round 9
// baseline (437.719 us; speedup 1.0000x reference)
//
#include <hip/hip_runtime.h>
#include <hip/hip_bf16.h>

#define NV 8192
#define FIN 128
#define FOUT 64

typedef __attribute__((ext_vector_type(8))) short short8;
typedef __attribute__((ext_vector_type(4))) float floatx4;

__device__ __forceinline__ uint f2bf_u(float f) {
  uint u = __float_as_uint(f);
  return (u + 0x7FFFu + ((u >> 16) & 1u)) >> 16;   // RTN-even bf16
}
__device__ __forceinline__ float bf2f(ushort b) {
  return __uint_as_float(((uint)b) << 16);
}

// ---------------------------------------------------------------------------
// Kernel 0: detect input dtype (fp32 vs packed bf16). flag=1 -> bf16 inputs.
// ---------------------------------------------------------------------------
__global__ void k0_detect(const uint* __restrict__ X, int* __restrict__ flag) {
  const int lane = threadIdx.x & 63;
  uint u = X[lane];
  uint e = (u >> 7) & 0xFF;
  bool ok = (e >= 100u) && (e <= 135u);
  unsigned long long b = __ballot(ok);
  if (lane == 0) *flag = (__builtin_popcountll(b) >= 48) ? 1 : 0;
}

// ---------------------------------------------------------------------------
// Kernel 1: h = X@W (MFMA) + s1/s2. h written PRE-SWIZZLED into MFMA
// B-fragment order (R6 version — numerically verified):
// HtB[chunk][kc][nt][lane][8 bf16], chunk = 64 global cols, 8 KB each.
// ---------------------------------------------------------------------------
__global__ __launch_bounds__(256) void k1_proj(
    const void* __restrict__ Xv, const void* __restrict__ Wv,
    const void* __restrict__ a1v_, const void* __restrict__ a2v_,
    ushort* __restrict__ HtB, float* __restrict__ s1, float* __restrict__ s2,
    const int* __restrict__ flagp)
{
  const int is_bf16 = *flagp;
  const int wave = threadIdx.x >> 6;
  const int lane = threadIdx.x & 63;
  const int i0 = blockIdx.x * 64 + wave * 16;
  const int col = lane & 15;
  const int q   = lane >> 4;

  short8 bfrag[4][4];
  float a1f[4], a2f[4];
  if (is_bf16) {
    const ushort* W = (const ushort*)Wv;
#pragma unroll
    for (int nt = 0; nt < 4; ++nt)
#pragma unroll
      for (int kc = 0; kc < 4; ++kc) {
        short8 b;
#pragma unroll
        for (int j = 0; j < 8; ++j)
          b[j] = (short)W[(kc*32 + q*8 + j)*FOUT + nt*16 + col];
        bfrag[nt][kc] = b;
      }
#pragma unroll
    for (int nt = 0; nt < 4; ++nt) {
      a1f[nt] = bf2f(((const ushort*)a1v_)[nt*16 + col]);
      a2f[nt] = bf2f(((const ushort*)a2v_)[nt*16 + col]);
    }
  } else {
    const float* W = (const float*)Wv;
#pragma unroll
    for (int nt = 0; nt < 4; ++nt)
#pragma unroll
      for (int kc = 0; kc < 4; ++kc) {
        short8 b;
#pragma unroll
        for (int j = 0; j < 8; ++j)
          b[j] = (short)f2bf_u(W[(kc*32 + q*8 + j)*FOUT + nt*16 + col]);
        bfrag[nt][kc] = b;
      }
#pragma unroll
    for (int nt = 0; nt < 4; ++nt) {
      a1f[nt] = ((const float*)a1v_)[nt*16 + col];
      a2f[nt] = ((const float*)a2v_)[nt*16 + col];
    }
  }

  floatx4 acc[4] = {{0.f,0.f,0.f,0.f},{0.f,0.f,0.f,0.f},
                    {0.f,0.f,0.f,0.f},{0.f,0.f,0.f,0.f}};
#pragma unroll
  for (int kc = 0; kc < 4; ++kc) {
    short8 a;
    if (is_bf16) {
      a = *(const short8*)&((const ushort*)Xv)[(size_t)(i0 + col)*FIN + kc*32 + q*8];
    } else {
      const float* X = (const float*)Xv;
      float4 x0 = *(const float4*)&X[(size_t)(i0 + col)*FIN + kc*32 + q*8];
      float4 x1 = *(const float4*)&X[(size_t)(i0 + col)*FIN + kc*32 + q*8 + 4];
      a[0] = (short)f2bf_u(x0.x); a[1] = (short)f2bf_u(x0.y);
      a[2] = (short)f2bf_u(x0.z); a[3] = (short)f2bf_u(x0.w);
      a[4] = (short)f2bf_u(x1.x); a[5] = (short)f2bf_u(x1.y);
      a[6] = (short)f2bf_u(x1.z); a[7] = (short)f2bf_u(x1.w);
    }
#pragma unroll
    for (int nt = 0; nt < 4; ++nt)
      acc[nt] = __builtin_amdgcn_mfma_f32_16x16x32_bf16(a, bfrag[nt][kc], acc[nt], 0, 0, 0);
  }

  // swizzled store into B-frag order (verified in R6)
  const int r0  = wave*16 + q*4;
  const int kcH = r0 >> 5;
  const int q2  = (r0 >> 3) & 3;
  const int j0  = r0 & 7;
  ushort* chunkp = HtB + (size_t)blockIdx.x * 4096;

  float s1p[4] = {0,0,0,0}, s2p[4] = {0,0,0,0};
#pragma unroll
  for (int nt = 0; nt < 4; ++nt) {
    ushort4 pk;
    pk.x = (ushort)f2bf_u(acc[nt][0]);
    pk.y = (ushort)f2bf_u(acc[nt][1]);
    pk.z = (ushort)f2bf_u(acc[nt][2]);
    pk.w = (ushort)f2bf_u(acc[nt][3]);
    *(ushort4*)&chunkp[((kcH*4 + nt)*64 + q2*16 + col)*8 + j0] = pk;
#pragma unroll
    for (int reg = 0; reg < 4; ++reg) {
      s1p[reg] += acc[nt][reg] * a1f[nt];
      s2p[reg] += acc[nt][reg] * a2f[nt];
    }
  }
#pragma unroll
  for (int m = 1; m < 16; m <<= 1)
#pragma unroll
    for (int reg = 0; reg < 4; ++reg) {
      s1p[reg] += __shfl_xor(s1p[reg], m, 64);
      s2p[reg] += __shfl_xor(s2p[reg], m, 64);
    }
  if (col == 0)
#pragma unroll
    for (int reg = 0; reg < 4; ++reg) {
      s1[i0 + q*4 + reg] = s1p[reg];
      s2[i0 + q*4 + reg] = s2p[reg];
    }
}

// ---------------------------------------------------------------------------
// Kernel 2: BARRIER-FREE sweep + 4-way slice split + deep FIFO prefetch.
// grid = 2048: slice sl = blk&3 (2048 cols), row-block rb = blk>>2 (16 rows).
// Each wave owns a 64-col chunk of each 256-col tile; 8 iterations/wave.
// P wave-private LDS (no s_barrier in the loop). B-frags from pre-swizzled
// HtB, register-prefetched one iteration ahead; A prefetched TWO ahead, so
// loads stay in flight across iterations (vmcnt(N), never a full drain).
// ---------------------------------------------------------------------------
#define SLICES 4
#define SW (NV / SLICES)   // 2048
#define NIT (SW / 256)     // 8 iterations of 256-col tiles
#define PST 72

__global__ __launch_bounds__(256, 4) void k2_attn(
    const int* __restrict__ A, const ushort* __restrict__ HtB,
    const float* __restrict__ s1g, const float* __restrict__ s2g,
    float* __restrict__ Part, float* __restrict__ Lpart)
{
  __shared__ __align__(16) ushort Pl[4][16 * PST];  //  9.2 KB wave-private P
  __shared__ __align__(16) float Red[4][16][64];    // 16   KB partials
  __shared__ float Lw[4][16];

  const int tid  = threadIdx.x;
  const int wave = tid >> 6;
  const int lane = tid & 63;
  const int sl   = blockIdx.x & (SLICES - 1);
  const int rb   = blockIdx.x >> 2;
  const int i0   = rb * 16;
  const int q    = lane >> 4;
  const int mcol = lane & 15;
  const int c0s  = sl * SW;
  const int t0   = (rb * 3) & (NIT - 1);   // phase stagger per row-block

  ushort* Pw = &Pl[wave][0];

  float s1v[4];
#pragma unroll
  for (int rr = 0; rr < 4; ++rr) s1v[rr] = s1g[i0 + q*4 + rr];

  size_t arow[4];
#pragma unroll
  for (int rr = 0; rr < 4; ++rr)
    arow[rr] = (size_t)(i0 + q*4 + rr) * NV + c0s + mcol*4;

  float Lp[4] = {0,0,0,0};
  floatx4 acc[4] = {{0.f,0.f,0.f,0.f},{0.f,0.f,0.f,0.f},
                    {0.f,0.f,0.f,0.f},{0.f,0.f,0.f,0.f}};

  // column offset (within slice) of iteration t for this wave
  #define OFF(t) ((((t) + t0) & (NIT - 1)) * 256 + wave * 64)
  // HtB chunk index of iteration t
  #define CHK(t) ((size_t)(sl*32 + (((t) + t0) & (NIT - 1))*4 + wave) * 4096)

  // ---- prologue: A for iters 0,1; B-frags for iter 0 ----
  int4 av[2][4];
  float4 sv[2];
#pragma unroll
  for (int s = 0; s < 2; ++s) {
    const int c = OFF(s);
#pragma unroll
    for (int rr = 0; rr < 4; ++rr) av[s][rr] = *(const int4*)&A[arow[rr] + c];
    sv[s] = *(const float4*)&s2g[c0s + c + mcol*4];
  }
  short8 bf[8];
  {
    const size_t cb = CHK(0);
#pragma unroll
    for (int k = 0; k < 8; ++k)
      bf[k] = *(const short8*)&HtB[cb + ((size_t)(k*64 + lane)) * 8];
  }

  for (int t = 0; t < NIT; ++t) {
    const int cur = t & 1;

    // ---- 1. exp + pack P from av[cur]/sv[cur] (wave-private, no barrier) --
#pragma unroll
    for (int rr = 0; rr < 4; ++rr) {
      const int4 a = av[cur][rr];
      const float s1r = s1v[rr];
      const float4 s2v = sv[cur];
      float x0 = s1r + s2v.x, x1 = s1r + s2v.y, x2 = s1r + s2v.z, x3 = s1r + s2v.w;
      float w0 = a.x ? __expf(fmaxf(x0, 0.2f*x0)) : 0.f;
      float w1 = a.y ? __expf(fmaxf(x1, 0.2f*x1)) : 0.f;
      float w2 = a.z ? __expf(fmaxf(x2, 0.2f*x2)) : 0.f;
      float w3 = a.w ? __expf(fmaxf(x3, 0.2f*x3)) : 0.f;
      Lp[rr] += (w0 + w1) + (w2 + w3);
      uint2 pk;
      pk.x = f2bf_u(w0) | (f2bf_u(w1) << 16);
      pk.y = f2bf_u(w2) | (f2bf_u(w3) << 16);
      *(uint2*)&Pw[(q*4 + rr)*PST + mcol*4] = pk;
    }

    // ---- 2. prefetch A two iterations ahead (stays in flight) ----
    {
      const int tn = (t + 2 < NIT) ? (t + 2) : t;
      const int c2 = OFF(tn);
#pragma unroll
      for (int rr = 0; rr < 4; ++rr) av[cur][rr] = *(const int4*)&A[arow[rr] + c2];
      sv[cur] = *(const float4*)&s2g[c0s + c2 + mcol*4];
    }

    // ---- 3. MFMA: A-frag from private P (lgkm), B-frag in registers ----
#pragma unroll
    for (int kc2 = 0; kc2 < 2; ++kc2) {
      short8 af = *(const short8*)&Pw[mcol*PST + kc2*32 + q*8];
#pragma unroll
      for (int nt = 0; nt < 4; ++nt)
        acc[nt] = __builtin_amdgcn_mfma_f32_16x16x32_bf16(af, bf[kc2*4 + nt], acc[nt], 0, 0, 0);
    }

    // ---- 4. prefetch next iteration's B-frags (L2-hot) ----
    {
      const int tb = (t + 1 < NIT) ? (t + 1) : t;
      const size_t cb = CHK(tb);
#pragma unroll
      for (int k = 0; k < 8; ++k)
        bf[k] = *(const short8*)&HtB[cb + ((size_t)(k*64 + lane)) * 8];
    }
  }

  // ---- per-wave row sums over its columns ----
#pragma unroll
  for (int m = 1; m < 16; m <<= 1)
#pragma unroll
    for (int rr = 0; rr < 4; ++rr) Lp[rr] += __shfl_xor(Lp[rr], m, 64);
  if (mcol == 0)
#pragma unroll
    for (int rr = 0; rr < 4; ++rr) Lw[wave][q*4 + rr] = Lp[rr];

  // partial accumulators to LDS (C/D: col=mcol, row=q*4+reg)
#pragma unroll
  for (int nt = 0; nt < 4; ++nt)
#pragma unroll
    for (int reg = 0; reg < 4; ++reg)
      Red[wave][q*4 + reg][nt*16 + mcol] = acc[nt][reg];

  __syncthreads();   // the only barrier

  // ---- combine 4 waves -> per-slice partials ----
  {
    const int r  = tid >> 4;
    const int fb = (tid & 15) * 4;
    float4 s = {0.f, 0.f, 0.f, 0.f};
    float L = 0.f;
#pragma unroll
    for (int w = 0; w < 4; ++w) {
      float4 v = *(const float4*)&Red[w][r][fb];
      s.x += v.x; s.y += v.y; s.z += v.z; s.w += v.w;
      L += Lw[w][r];
    }
    *(float4*)&Part[((size_t)sl * NV + i0 + r) * FOUT + fb] = s;
    if ((tid & 15) == 0) Lpart[(size_t)sl * NV + i0 + r] = L;
  }
}

// ---------------------------------------------------------------------------
// Kernel 3: combine 4 slices, divide, store.
// ---------------------------------------------------------------------------
__global__ __launch_bounds__(256) void k3_combine(
    const float* __restrict__ Part, const float* __restrict__ Lpart,
    void* __restrict__ outv, const int* __restrict__ flagp)
{
  const int is_bf16 = *flagp;
  const int g   = blockIdx.x * 256 + threadIdx.x;
  const int row = g >> 4;
  const int fb  = (g & 15) * 4;

  float4 s = {0.f, 0.f, 0.f, 0.f};
  float L = 0.f;
#pragma unroll
  for (int sl = 0; sl < SLICES; ++sl) {
    float4 v = *(const float4*)&Part[((size_t)sl * NV + row) * FOUT + fb];
    s.x += v.x; s.y += v.y; s.z += v.z; s.w += v.w;
    L += Lpart[(size_t)sl * NV + row];
  }
  const float inv = __frcp_rn(L);
  s.x *= inv; s.y *= inv; s.z *= inv; s.w *= inv;
  if (is_bf16) {
    ushort4 pk;
    pk.x = (ushort)f2bf_u(s.x); pk.y = (ushort)f2bf_u(s.y);
    pk.z = (ushort)f2bf_u(s.z); pk.w = (ushort)f2bf_u(s.w);
    *(ushort4*)&((ushort*)outv)[(size_t)row * FOUT + fb] = pk;
  } else {
    *(float4*)&((float*)outv)[(size_t)row * FOUT + fb] = s;
  }
}

extern "C" void kernel_launch(void* const* d_in, const int* in_sizes, int n_in,
                              void* d_out, int out_size, void* d_ws, size_t ws_size,
                              hipStream_t stream) {
  const void* X  = d_in[0];                 // f32 (or bf16) [8192][128]
  const int*  A  = (const int*)d_in[1];     // int32 [8192][8192]
  const void* W  = d_in[2];                 // f32 (or bf16) [128][64]
  const void* a1 = d_in[3];                 // f32 (or bf16) [64]
  const void* a2 = d_in[4];                 // f32 (or bf16) [64]

  char* ws = (char*)d_ws;
  ushort* HtB   = (ushort*)ws;                         // 1 MiB
  float*  s1    = (float*)(ws + (size_t)FOUT*NV*2);    // 32 KiB
  float*  s2    = s1 + NV;                             // 32 KiB
  int*    flag  = (int*)(s2 + NV);                     // 16 B (padded)
  float*  Part  = (float*)((char*)flag + 16);          // 8 MiB
  float*  Lpart = Part + (size_t)SLICES * NV * FOUT;   // 128 KiB

  hipLaunchKernelGGL(k0_detect, dim3(1), dim3(64), 0, stream,
                     (const uint*)X, flag);
  hipLaunchKernelGGL(k1_proj, dim3(NV/64), dim3(256), 0, stream,
                     X, W, a1, a2, HtB, s1, s2, flag);
  hipLaunchKernelGGL(k2_attn, dim3((NV/16) * SLICES), dim3(256), 0, stream,
                     A, HtB, s1, s2, Part, Lpart);
  hipLaunchKernelGGL(k3_combine, dim3(NV*FOUT/4/256), dim3(256), 0, stream,
                     Part, Lpart, d_out, flag);
}

// Round 10
// 425.699 us; speedup vs baseline: 1.0282x; 1.0282x over previous
//
#include <hip/hip_runtime.h>
#include <hip/hip_bf16.h>

#define NV 8192
#define FIN 128
#define FOUT 64

typedef __attribute__((ext_vector_type(8))) short short8;
typedef __attribute__((ext_vector_type(4))) float floatx4;
typedef __attribute__((ext_vector_type(4))) int intx4;

__device__ __forceinline__ uint f2bf_u(float f) {
  uint u = __float_as_uint(f);
  return (u + 0x7FFFu + ((u >> 16) & 1u)) >> 16;   // RTN-even bf16
}
__device__ __forceinline__ float bf2f(ushort b) {
  return __uint_as_float(((uint)b) << 16);
}
// Non-temporal 16B load: nt flag -> no L2/L3 allocation, no dirty evictions.
__device__ __forceinline__ intx4 ntload4(const int* p) {
  return __builtin_nontemporal_load((const intx4*)p);
}

// ---------------------------------------------------------------------------
// Kernel 0: detect input dtype (fp32 vs packed bf16). flag=1 -> bf16 inputs.
// ---------------------------------------------------------------------------
__global__ void k0_detect(const uint* __restrict__ X, int* __restrict__ flag) {
  const int lane = threadIdx.x & 63;
  uint u = X[lane];
  uint e = (u >> 7) & 0xFF;
  bool ok = (e >= 100u) && (e <= 135u);
  unsigned long long b = __ballot(ok);
  if (lane == 0) *flag = (__builtin_popcountll(b) >= 48) ? 1 : 0;
}

// ---------------------------------------------------------------------------
// Kernel 1: h = X@W (MFMA) + s1/s2. h written PRE-SWIZZLED into MFMA
// B-fragment order: HtB[chunk][kc][nt][lane][8 bf16], 8 KB per 64-col chunk.
// ---------------------------------------------------------------------------
__global__ __launch_bounds__(256) void k1_proj(
    const void* __restrict__ Xv, const void* __restrict__ Wv,
    const void* __restrict__ a1v_, const void* __restrict__ a2v_,
    ushort* __restrict__ HtB, float* __restrict__ s1, float* __restrict__ s2,
    const int* __restrict__ flagp)
{
  const int is_bf16 = *flagp;
  const int wave = threadIdx.x >> 6;
  const int lane = threadIdx.x & 63;
  const int i0 = blockIdx.x * 64 + wave * 16;
  const int col = lane & 15;
  const int q   = lane >> 4;

  short8 bfrag[4][4];
  float a1f[4], a2f[4];
  if (is_bf16) {
    const ushort* W = (const ushort*)Wv;
#pragma unroll
    for (int nt = 0; nt < 4; ++nt)
#pragma unroll
      for (int kc = 0; kc < 4; ++kc) {
        short8 b;
#pragma unroll
        for (int j = 0; j < 8; ++j)
          b[j] = (short)W[(kc*32 + q*8 + j)*FOUT + nt*16 + col];
        bfrag[nt][kc] = b;
      }
#pragma unroll
    for (int nt = 0; nt < 4; ++nt) {
      a1f[nt] = bf2f(((const ushort*)a1v_)[nt*16 + col]);
      a2f[nt] = bf2f(((const ushort*)a2v_)[nt*16 + col]);
    }
  } else {
    const float* W = (const float*)Wv;
#pragma unroll
    for (int nt = 0; nt < 4; ++nt)
#pragma unroll
      for (int kc = 0; kc < 4; ++kc) {
        short8 b;
#pragma unroll
        for (int j = 0; j < 8; ++j)
          b[j] = (short)f2bf_u(W[(kc*32 + q*8 + j)*FOUT + nt*16 + col]);
        bfrag[nt][kc] = b;
      }
#pragma unroll
    for (int nt = 0; nt < 4; ++nt) {
      a1f[nt] = ((const float*)a1v_)[nt*16 + col];
      a2f[nt] = ((const float*)a2v_)[nt*16 + col];
    }
  }

  floatx4 acc[4] = {{0.f,0.f,0.f,0.f},{0.f,0.f,0.f,0.f},
                    {0.f,0.f,0.f,0.f},{0.f,0.f,0.f,0.f}};
#pragma unroll
  for (int kc = 0; kc < 4; ++kc) {
    short8 a;
    if (is_bf16) {
      a = *(const short8*)&((const ushort*)Xv)[(size_t)(i0 + col)*FIN + kc*32 + q*8];
    } else {
      const float* X = (const float*)Xv;
      float4 x0 = *(const float4*)&X[(size_t)(i0 + col)*FIN + kc*32 + q*8];
      float4 x1 = *(const float4*)&X[(size_t)(i0 + col)*FIN + kc*32 + q*8 + 4];
      a[0] = (short)f2bf_u(x0.x); a[1] = (short)f2bf_u(x0.y);
      a[2] = (short)f2bf_u(x0.z); a[3] = (short)f2bf_u(x0.w);
      a[4] = (short)f2bf_u(x1.x); a[5] = (short)f2bf_u(x1.y);
      a[6] = (short)f2bf_u(x1.z); a[7] = (short)f2bf_u(x1.w);
    }
#pragma unroll
    for (int nt = 0; nt < 4; ++nt)
      acc[nt] = __builtin_amdgcn_mfma_f32_16x16x32_bf16(a, bfrag[nt][kc], acc[nt], 0, 0, 0);
  }

  // swizzled store into B-frag order (verified R6/R9)
  const int r0  = wave*16 + q*4;
  const int kcH = r0 >> 5;
  const int q2  = (r0 >> 3) & 3;
  const int j0  = r0 & 7;
  ushort* chunkp = HtB + (size_t)blockIdx.x * 4096;

  float s1p[4] = {0,0,0,0}, s2p[4] = {0,0,0,0};
#pragma unroll
  for (int nt = 0; nt < 4; ++nt) {
    ushort4 pk;
    pk.x = (ushort)f2bf_u(acc[nt][0]);
    pk.y = (ushort)f2bf_u(acc[nt][1]);
    pk.z = (ushort)f2bf_u(acc[nt][2]);
    pk.w = (ushort)f2bf_u(acc[nt][3]);
    *(ushort4*)&chunkp[((kcH*4 + nt)*64 + q2*16 + col)*8 + j0] = pk;
#pragma unroll
    for (int reg = 0; reg < 4; ++reg) {
      s1p[reg] += acc[nt][reg] * a1f[nt];
      s2p[reg] += acc[nt][reg] * a2f[nt];
    }
  }
#pragma unroll
  for (int m = 1; m < 16; m <<= 1)
#pragma unroll
    for (int reg = 0; reg < 4; ++reg) {
      s1p[reg] += __shfl_xor(s1p[reg], m, 64);
      s2p[reg] += __shfl_xor(s2p[reg], m, 64);
    }
  if (col == 0)
#pragma unroll
    for (int reg = 0; reg < 4; ++reg) {
      s1[i0 + q*4 + reg] = s1p[reg];
      s2[i0 + q*4 + reg] = s2p[reg];
    }
}

// ---------------------------------------------------------------------------
// Kernel 2: barrier-free sweep + 4-way slice split + FIFO prefetch + NT A.
// A loads are NON-TEMPORAL: no L3 allocation -> the harness's dirty poison
// stays put (no 200 MB eviction write-back: R9's WRITE_SIZE smoking gun),
// and no read/write channel turnaround. Tail prefetches are guarded so no
// load is ever issued twice (nt data won't linger in L2).
// ---------------------------------------------------------------------------
#define SLICES 4
#define SW (NV / SLICES)   // 2048
#define NIT (SW / 256)     // 8 iterations of 256-col tiles
#define PST 72

__global__ __launch_bounds__(256, 4) void k2_attn(
    const int* __restrict__ A, const ushort* __restrict__ HtB,
    const float* __restrict__ s1g, const float* __restrict__ s2g,
    float* __restrict__ Part, float* __restrict__ Lpart)
{
  __shared__ __align__(16) ushort Pl[4][16 * PST];  //  9.2 KB wave-private P
  __shared__ __align__(16) float Red[4][16][64];    // 16   KB partials
  __shared__ float Lw[4][16];

  const int tid  = threadIdx.x;
  const int wave = tid >> 6;
  const int lane = tid & 63;
  const int sl   = blockIdx.x & (SLICES - 1);
  const int rb   = blockIdx.x >> 2;
  const int i0   = rb * 16;
  const int q    = lane >> 4;
  const int mcol = lane & 15;
  const int c0s  = sl * SW;
  const int t0   = (rb * 3) & (NIT - 1);   // phase stagger per row-block

  ushort* Pw = &Pl[wave][0];

  float s1v[4];
#pragma unroll
  for (int rr = 0; rr < 4; ++rr) s1v[rr] = s1g[i0 + q*4 + rr];

  size_t arow[4];
#pragma unroll
  for (int rr = 0; rr < 4; ++rr)
    arow[rr] = (size_t)(i0 + q*4 + rr) * NV + c0s + mcol*4;

  float Lp[4] = {0,0,0,0};
  floatx4 acc[4] = {{0.f,0.f,0.f,0.f},{0.f,0.f,0.f,0.f},
                    {0.f,0.f,0.f,0.f},{0.f,0.f,0.f,0.f}};

  #define OFF(t) ((((t) + t0) & (NIT - 1)) * 256 + wave * 64)
  #define CHK(t) ((size_t)(sl*32 + (((t) + t0) & (NIT - 1))*4 + wave) * 4096)

  // ---- prologue: A for iters 0,1 (nt); B-frags for iter 0 ----
  intx4 av[2][4];
  float4 sv[2];
#pragma unroll
  for (int s = 0; s < 2; ++s) {
    const int c = OFF(s);
#pragma unroll
    for (int rr = 0; rr < 4; ++rr) av[s][rr] = ntload4(&A[arow[rr] + c]);
    sv[s] = *(const float4*)&s2g[c0s + c + mcol*4];
  }
  short8 bf[8];
  {
    const size_t cb = CHK(0);
#pragma unroll
    for (int k = 0; k < 8; ++k)
      bf[k] = *(const short8*)&HtB[cb + ((size_t)(k*64 + lane)) * 8];
  }

  for (int t = 0; t < NIT; ++t) {
    const int cur = t & 1;

    // ---- 1. exp + pack P (wave-private, no barrier) ----
#pragma unroll
    for (int rr = 0; rr < 4; ++rr) {
      const intx4 a = av[cur][rr];
      const float s1r = s1v[rr];
      const float4 s2v = sv[cur];
      float x0 = s1r + s2v.x, x1 = s1r + s2v.y, x2 = s1r + s2v.z, x3 = s1r + s2v.w;
      float w0 = a[0] ? __expf(fmaxf(x0, 0.2f*x0)) : 0.f;
      float w1 = a[1] ? __expf(fmaxf(x1, 0.2f*x1)) : 0.f;
      float w2 = a[2] ? __expf(fmaxf(x2, 0.2f*x2)) : 0.f;
      float w3 = a[3] ? __expf(fmaxf(x3, 0.2f*x3)) : 0.f;
      Lp[rr] += (w0 + w1) + (w2 + w3);
      uint2 pk;
      pk.x = f2bf_u(w0) | (f2bf_u(w1) << 16);
      pk.y = f2bf_u(w2) | (f2bf_u(w3) << 16);
      *(uint2*)&Pw[(q*4 + rr)*PST + mcol*4] = pk;
    }

    // ---- 2. prefetch A two ahead (nt, stays in flight; no tail re-issue) --
    if (t + 2 < NIT) {
      const int c2 = OFF(t + 2);
#pragma unroll
      for (int rr = 0; rr < 4; ++rr) av[cur][rr] = ntload4(&A[arow[rr] + c2]);
      sv[cur] = *(const float4*)&s2g[c0s + c2 + mcol*4];
    }

    // ---- 3. MFMA: A-frag from private P (lgkm), B-frags in registers ----
#pragma unroll
    for (int kc2 = 0; kc2 < 2; ++kc2) {
      short8 af = *(const short8*)&Pw[mcol*PST + kc2*32 + q*8];
#pragma unroll
      for (int nt = 0; nt < 4; ++nt)
        acc[nt] = __builtin_amdgcn_mfma_f32_16x16x32_bf16(af, bf[kc2*4 + nt], acc[nt], 0, 0, 0);
    }

    // ---- 4. prefetch next iteration's B-frags (temporal, L2-hot) ----
    if (t + 1 < NIT) {
      const size_t cb = CHK(t + 1);
#pragma unroll
      for (int k = 0; k < 8; ++k)
        bf[k] = *(const short8*)&HtB[cb + ((size_t)(k*64 + lane)) * 8];
    }
  }

  // ---- per-wave row sums over its columns ----
#pragma unroll
  for (int m = 1; m < 16; m <<= 1)
#pragma unroll
    for (int rr = 0; rr < 4; ++rr) Lp[rr] += __shfl_xor(Lp[rr], m, 64);
  if (mcol == 0)
#pragma unroll
    for (int rr = 0; rr < 4; ++rr) Lw[wave][q*4 + rr] = Lp[rr];

  // partial accumulators to LDS (C/D: col=mcol, row=q*4+reg)
#pragma unroll
  for (int nt = 0; nt < 4; ++nt)
#pragma unroll
    for (int reg = 0; reg < 4; ++reg)
      Red[wave][q*4 + reg][nt*16 + mcol] = acc[nt][reg];

  __syncthreads();   // the only barrier

  // ---- combine 4 waves -> per-slice partials ----
  {
    const int r  = tid >> 4;
    const int fb = (tid & 15) * 4;
    float4 s = {0.f, 0.f, 0.f, 0.f};
    float L = 0.f;
#pragma unroll
    for (int w = 0; w < 4; ++w) {
      float4 v = *(const float4*)&Red[w][r][fb];
      s.x += v.x; s.y += v.y; s.z += v.z; s.w += v.w;
      L += Lw[w][r];
    }
    *(float4*)&Part[((size_t)sl * NV + i0 + r) * FOUT + fb] = s;
    if ((tid & 15) == 0) Lpart[(size_t)sl * NV + i0 + r] = L;
  }
}

// ---------------------------------------------------------------------------
// Kernel 3: combine 4 slices, divide, store.
// ---------------------------------------------------------------------------
__global__ __launch_bounds__(256) void k3_combine(
    const float* __restrict__ Part, const float* __restrict__ Lpart,
    void* __restrict__ outv, const int* __restrict__ flagp)
{
  const int is_bf16 = *flagp;
  const int g   = blockIdx.x * 256 + threadIdx.x;
  const int row = g >> 4;
  const int fb  = (g & 15) * 4;

  float4 s = {0.f, 0.f, 0.f, 0.f};
  float L = 0.f;
#pragma unroll
  for (int sl = 0; sl < SLICES; ++sl) {
    float4 v = *(const float4*)&Part[((size_t)sl * NV + row) * FOUT + fb];
    s.x += v.x; s.y += v.y; s.z += v.z; s.w += v.w;
    L += Lpart[(size_t)sl * NV + row];
  }
  const float inv = __frcp_rn(L);
  s.x *= inv; s.y *= inv; s.z *= inv; s.w *= inv;
  if (is_bf16) {
    ushort4 pk;
    pk.x = (ushort)f2bf_u(s.x); pk.y = (ushort)f2bf_u(s.y);
    pk.z = (ushort)f2bf_u(s.z); pk.w = (ushort)f2bf_u(s.w);
    *(ushort4*)&((ushort*)outv)[(size_t)row * FOUT + fb] = pk;
  } else {
    *(float4*)&((float*)outv)[(size_t)row * FOUT + fb] = s;
  }
}

extern "C" void kernel_launch(void* const* d_in, const int* in_sizes, int n_in,
                              void* d_out, int out_size, void* d_ws, size_t ws_size,
                              hipStream_t stream) {
  const void* X  = d_in[0];                 // f32 (or bf16) [8192][128]
  const int*  A  = (const int*)d_in[1];     // int32 [8192][8192]
  const void* W  = d_in[2];                 // f32 (or bf16) [128][64]
  const void* a1 = d_in[3];                 // f32 (or bf16) [64]
  const void* a2 = d_in[4];                 // f32 (or bf16) [64]

  char* ws = (char*)d_ws;
  ushort* HtB   = (ushort*)ws;                         // 1 MiB
  float*  s1    = (float*)(ws + (size_t)FOUT*NV*2);    // 32 KiB
  float*  s2    = s1 + NV;                             // 32 KiB
  int*    flag  = (int*)(s2 + NV);                     // 16 B (padded)
  float*  Part  = (float*)((char*)flag + 16);          // 8 MiB
  float*  Lpart = Part + (size_t)SLICES * NV * FOUT;   // 128 KiB

  hipLaunchKernelGGL(k0_detect, dim3(1), dim3(64), 0, stream,
                     (const uint*)X, flag);
  hipLaunchKernelGGL(k1_proj, dim3(NV/64), dim3(256), 0, stream,
                     X, W, a1, a2, HtB, s1, s2, flag);
  hipLaunchKernelGGL(k2_attn, dim3((NV/16) * SLICES), dim3(256), 0, stream,
                     A, HtB, s1, s2, Part, Lpart);
  hipLaunchKernelGGL(k3_combine, dim3(NV*FOUT/4/256), dim3(256), 0, stream,
                     Part, Lpart, d_out, flag);
}

// Round 11
// 375.716 us; speedup vs baseline: 1.1650x; 1.1330x over previous
//
#include <hip/hip_runtime.h>
#include <hip/hip_bf16.h>

#define NV 8192
#define FIN 128
#define FOUT 64

typedef __attribute__((ext_vector_type(8))) short short8;
typedef __attribute__((ext_vector_type(4))) float floatx4;
typedef __attribute__((ext_vector_type(4))) int intx4;

__device__ __forceinline__ uint f2bf_u(float f) {
  uint u = __float_as_uint(f);
  return (u + 0x7FFFu + ((u >> 16) & 1u)) >> 16;   // RTN-even bf16
}
__device__ __forceinline__ float bf2f(ushort b) {
  return __uint_as_float(((uint)b) << 16);
}
// Non-temporal 16B load: hits still served from cache; misses don't allocate
// -> no dirty-poison eviction write-back (R9's 202 MB WRITE_SIZE smoking gun).
__device__ __forceinline__ intx4 ntload4(const int* p) {
  return __builtin_nontemporal_load((const intx4*)p);
}

// ---------------------------------------------------------------------------
// Kernel 0: detect input dtype (fp32 vs packed bf16). flag=1 -> bf16 inputs.
// ---------------------------------------------------------------------------
__global__ void k0_detect(const uint* __restrict__ X, int* __restrict__ flag) {
  const int lane = threadIdx.x & 63;
  uint u = X[lane];
  uint e = (u >> 7) & 0xFF;
  bool ok = (e >= 100u) && (e <= 135u);
  unsigned long long b = __ballot(ok);
  if (lane == 0) *flag = (__builtin_popcountll(b) >= 48) ? 1 : 0;
}

// ---------------------------------------------------------------------------
// Kernel 1: h = X@W (MFMA), write Ht (bf16, [64][8192]) + s1/s2 (fp32).
// (R5/R7 version — proven)
// ---------------------------------------------------------------------------
__global__ __launch_bounds__(256) void k1_proj(
    const void* __restrict__ Xv, const void* __restrict__ Wv,
    const void* __restrict__ a1v_, const void* __restrict__ a2v_,
    ushort* __restrict__ HtT, float* __restrict__ s1, float* __restrict__ s2,
    const int* __restrict__ flagp)
{
  const int is_bf16 = *flagp;
  const int wave = threadIdx.x >> 6;
  const int lane = threadIdx.x & 63;
  const int i0 = blockIdx.x * 64 + wave * 16;
  const int col = lane & 15;
  const int q   = lane >> 4;

  short8 bfrag[4][4];
  float a1f[4], a2f[4];
  if (is_bf16) {
    const ushort* W = (const ushort*)Wv;
#pragma unroll
    for (int nt = 0; nt < 4; ++nt)
#pragma unroll
      for (int kc = 0; kc < 4; ++kc) {
        short8 b;
#pragma unroll
        for (int j = 0; j < 8; ++j)
          b[j] = (short)W[(kc*32 + q*8 + j)*FOUT + nt*16 + col];
        bfrag[nt][kc] = b;
      }
#pragma unroll
    for (int nt = 0; nt < 4; ++nt) {
      a1f[nt] = bf2f(((const ushort*)a1v_)[nt*16 + col]);
      a2f[nt] = bf2f(((const ushort*)a2v_)[nt*16 + col]);
    }
  } else {
    const float* W = (const float*)Wv;
#pragma unroll
    for (int nt = 0; nt < 4; ++nt)
#pragma unroll
      for (int kc = 0; kc < 4; ++kc) {
        short8 b;
#pragma unroll
        for (int j = 0; j < 8; ++j)
          b[j] = (short)f2bf_u(W[(kc*32 + q*8 + j)*FOUT + nt*16 + col]);
        bfrag[nt][kc] = b;
      }
#pragma unroll
    for (int nt = 0; nt < 4; ++nt) {
      a1f[nt] = ((const float*)a1v_)[nt*16 + col];
      a2f[nt] = ((const float*)a2v_)[nt*16 + col];
    }
  }

  floatx4 acc[4] = {{0.f,0.f,0.f,0.f},{0.f,0.f,0.f,0.f},
                    {0.f,0.f,0.f,0.f},{0.f,0.f,0.f,0.f}};
#pragma unroll
  for (int kc = 0; kc < 4; ++kc) {
    short8 a;
    if (is_bf16) {
      a = *(const short8*)&((const ushort*)Xv)[(size_t)(i0 + col)*FIN + kc*32 + q*8];
    } else {
      const float* X = (const float*)Xv;
      float4 x0 = *(const float4*)&X[(size_t)(i0 + col)*FIN + kc*32 + q*8];
      float4 x1 = *(const float4*)&X[(size_t)(i0 + col)*FIN + kc*32 + q*8 + 4];
      a[0] = (short)f2bf_u(x0.x); a[1] = (short)f2bf_u(x0.y);
      a[2] = (short)f2bf_u(x0.z); a[3] = (short)f2bf_u(x0.w);
      a[4] = (short)f2bf_u(x1.x); a[5] = (short)f2bf_u(x1.y);
      a[6] = (short)f2bf_u(x1.z); a[7] = (short)f2bf_u(x1.w);
    }
#pragma unroll
    for (int nt = 0; nt < 4; ++nt)
      acc[nt] = __builtin_amdgcn_mfma_f32_16x16x32_bf16(a, bfrag[nt][kc], acc[nt], 0, 0, 0);
  }

  float s1p[4] = {0,0,0,0}, s2p[4] = {0,0,0,0};
#pragma unroll
  for (int nt = 0; nt < 4; ++nt) {
    ushort4 pk;
    pk.x = (ushort)f2bf_u(acc[nt][0]);
    pk.y = (ushort)f2bf_u(acc[nt][1]);
    pk.z = (ushort)f2bf_u(acc[nt][2]);
    pk.w = (ushort)f2bf_u(acc[nt][3]);
    *(ushort4*)&HtT[(size_t)(nt*16 + col)*NV + i0 + q*4] = pk;
#pragma unroll
    for (int reg = 0; reg < 4; ++reg) {
      s1p[reg] += acc[nt][reg] * a1f[nt];
      s2p[reg] += acc[nt][reg] * a2f[nt];
    }
  }
#pragma unroll
  for (int m = 1; m < 16; m <<= 1)
#pragma unroll
    for (int reg = 0; reg < 4; ++reg) {
      s1p[reg] += __shfl_xor(s1p[reg], m, 64);
      s2p[reg] += __shfl_xor(s2p[reg], m, 64);
    }
  if (col == 0)
#pragma unroll
    for (int reg = 0; reg < 4; ++reg) {
      s1[i0 + q*4 + reg] = s1p[reg];
      s2[i0 + q*4 + reg] = s2p[reg];
    }
}

// ---------------------------------------------------------------------------
// Kernel 2 (R7 — best measured structure — with NON-TEMPORAL A loads):
// staged 2-barrier loop, CT=128, per-block column-phase stagger. The only
// change vs R7: A reads carry the nt flag, so resident lines still hit but
// misses don't allocate -> no dirty-poison eviction stream, no RW turnaround.
// ---------------------------------------------------------------------------
#define CT 128
#define NT (NV / CT)       // 64 tiles
#define PST 136            // 128+8 bf16; 272 B row stride, uniform banks

__global__ __launch_bounds__(256, 6) void k2_attn(
    const int* __restrict__ A, const ushort* __restrict__ HtT,
    const float* __restrict__ s1g, const float* __restrict__ s2g,
    void* __restrict__ outv, const int* __restrict__ flagp)
{
  __shared__ __align__(16) ushort Pl[16 * PST];   //  4.25 KB
  __shared__ __align__(16) ushort Hl[64 * PST];   // 17    KB
  __shared__ float Lrow[16];

  const int is_bf16 = *flagp;
  const int tid  = threadIdx.x;
  const int wave = tid >> 6;
  const int lane = tid & 63;
  const int i0   = blockIdx.x * 16;
  const int q    = lane >> 4;
  const int mcol = lane & 15;
  const int r    = tid >> 4;        // 0..15: row this thread exp-processes
  const int cb   = (tid & 15) * 8;  // col offset in tile (8 cols/thread)
  const int t0   = (blockIdx.x * 23) & (NT - 1);   // column-phase stagger

  const float s1r = s1g[i0 + r];
  const size_t abase = (size_t)(i0 + r) * NV + cb;

  float Lp = 0.f;
  floatx4 acc = {0.f, 0.f, 0.f, 0.f};

  // ---- prefetch first tile (phase t0) ----
  intx4 av0, av1;
  float4 sv0, sv1;
  short8 hv[4];
  {
    const int c = t0 * CT;
    av0 = ntload4(&A[abase + c]);
    av1 = ntload4(&A[abase + c + 4]);
    sv0 = *(const float4*)&s2g[c + cb];
    sv1 = *(const float4*)&s2g[c + cb + 4];
#pragma unroll
    for (int it = 0; it < 4; ++it)
      hv[it] = *(const short8*)&HtT[(size_t)(r + 16*it) * NV + c + cb];
  }

  for (int t = 0; t < NT; ++t) {
    __syncthreads();   // Pl/Hl free (prev MFMA done); drains prefetch vmem

    // ---- stage: exp + pack P, copy Ht tile ----
    {
      float x0 = s1r + sv0.x, x1 = s1r + sv0.y, x2 = s1r + sv0.z, x3 = s1r + sv0.w;
      float x4 = s1r + sv1.x, x5 = s1r + sv1.y, x6 = s1r + sv1.z, x7 = s1r + sv1.w;
      float w0 = av0[0] ? __expf(fmaxf(x0, 0.2f*x0)) : 0.f;
      float w1 = av0[1] ? __expf(fmaxf(x1, 0.2f*x1)) : 0.f;
      float w2 = av0[2] ? __expf(fmaxf(x2, 0.2f*x2)) : 0.f;
      float w3 = av0[3] ? __expf(fmaxf(x3, 0.2f*x3)) : 0.f;
      float w4 = av1[0] ? __expf(fmaxf(x4, 0.2f*x4)) : 0.f;
      float w5 = av1[1] ? __expf(fmaxf(x5, 0.2f*x5)) : 0.f;
      float w6 = av1[2] ? __expf(fmaxf(x6, 0.2f*x6)) : 0.f;
      float w7 = av1[3] ? __expf(fmaxf(x7, 0.2f*x7)) : 0.f;
      Lp += ((w0 + w1) + (w2 + w3)) + ((w4 + w5) + (w6 + w7));
      uint4 pk;
      pk.x = f2bf_u(w0) | (f2bf_u(w1) << 16);
      pk.y = f2bf_u(w2) | (f2bf_u(w3) << 16);
      pk.z = f2bf_u(w4) | (f2bf_u(w5) << 16);
      pk.w = f2bf_u(w6) | (f2bf_u(w7) << 16);
      *(uint4*)&Pl[r * PST + cb] = pk;
#pragma unroll
      for (int it = 0; it < 4; ++it)
        *(short8*)&Hl[(r + 16*it) * PST + cb] = hv[it];
    }

    __syncthreads();   // publish

    // ---- prefetch next tile (flies across the MFMA phase) ----
    if (t + 1 < NT) {
      const int c2 = ((t + 1 + t0) & (NT - 1)) * CT;
      av0 = ntload4(&A[abase + c2]);
      av1 = ntload4(&A[abase + c2 + 4]);
      sv0 = *(const float4*)&s2g[c2 + cb];
      sv1 = *(const float4*)&s2g[c2 + cb + 4];
#pragma unroll
      for (int it = 0; it < 4; ++it)
        hv[it] = *(const short8*)&HtT[(size_t)(r + 16*it) * NV + c2 + cb];
    }

    // ---- MFMA: wave w computes out[0:16, w*16:(w+1)*16] ----
#pragma unroll
    for (int kc = 0; kc < 4; ++kc) {
      short8 af = *(const short8*)&Pl[mcol * PST + kc*32 + q*8];
      short8 bf = *(const short8*)&Hl[(wave*16 + mcol) * PST + kc*32 + q*8];
      acc = __builtin_amdgcn_mfma_f32_16x16x32_bf16(af, bf, acc, 0, 0, 0);
    }
  }

  // ---- denominators: reduce Lp over the 16 lanes sharing row r ----
#pragma unroll
  for (int m = 1; m < 16; m <<= 1) Lp += __shfl_xor(Lp, m, 64);
  if (mcol == 0) Lrow[r] = Lp;
  __syncthreads();

  // ---- epilogue: divide + store. C/D: col=mcol, row=q*4+reg ----
#pragma unroll
  for (int reg = 0; reg < 4; ++reg) {
    int rr = q*4 + reg;
    float v = acc[reg] / Lrow[rr];
    if (is_bf16)
      ((ushort*)outv)[(size_t)(i0 + rr)*FOUT + wave*16 + mcol] = (ushort)f2bf_u(v);
    else
      ((float*)outv)[(size_t)(i0 + rr)*FOUT + wave*16 + mcol] = v;
  }
}

extern "C" void kernel_launch(void* const* d_in, const int* in_sizes, int n_in,
                              void* d_out, int out_size, void* d_ws, size_t ws_size,
                              hipStream_t stream) {
  const void* X  = d_in[0];                 // f32 (or bf16) [8192][128]
  const int*  A  = (const int*)d_in[1];     // int32 [8192][8192]
  const void* W  = d_in[2];                 // f32 (or bf16) [128][64]
  const void* a1 = d_in[3];                 // f32 (or bf16) [64]
  const void* a2 = d_in[4];                 // f32 (or bf16) [64]

  char* ws = (char*)d_ws;
  ushort* HtT  = (ushort*)ws;                        // 1 MiB
  float*  s1   = (float*)(ws + (size_t)FOUT*NV*2);   // 32 KiB
  float*  s2   = s1 + NV;                            // 32 KiB
  int*    flag = (int*)(s2 + NV);                    // 4 B

  hipLaunchKernelGGL(k0_detect, dim3(1), dim3(64), 0, stream,
                     (const uint*)X, flag);
  hipLaunchKernelGGL(k1_proj, dim3(NV/64), dim3(256), 0, stream,
                     X, W, a1, a2, HtT, s1, s2, flag);
  hipLaunchKernelGGL(k2_attn, dim3(NV/16), dim3(256), 0, stream,
                     A, HtT, s1, s2, d_out, flag);
}

// Round 12
// 370.254 us; speedup vs baseline: 1.1822x; 1.0148x over previous
//
#include <hip/hip_runtime.h>
#include <hip/hip_bf16.h>

#define NV 8192
#define FIN 128
#define FOUT 64

typedef __attribute__((ext_vector_type(8))) short short8;
typedef __attribute__((ext_vector_type(4))) float floatx4;

__device__ __forceinline__ uint f2bf_u(float f) {
  uint u = __float_as_uint(f);
  return (u + 0x7FFFu + ((u >> 16) & 1u)) >> 16;   // RTN-even bf16
}
__device__ __forceinline__ float bf2f(ushort b) {
  return __uint_as_float(((uint)b) << 16);
}

// ---------------------------------------------------------------------------
// Kernel 0: detect input dtype (fp32 vs packed bf16). flag=1 -> bf16 inputs.
// ---------------------------------------------------------------------------
__global__ void k0_detect(const uint* __restrict__ X, int* __restrict__ flag) {
  const int lane = threadIdx.x & 63;
  uint u = X[lane];
  uint e = (u >> 7) & 0xFF;
  bool ok = (e >= 100u) && (e <= 135u);
  unsigned long long b = __ballot(ok);
  if (lane == 0) *flag = (__builtin_popcountll(b) >= 48) ? 1 : 0;
}

// ---------------------------------------------------------------------------
// Kernel 1: h = X@W (MFMA), write Ht (bf16, [64][8192]) + s1/s2 (fp32).
// (R5/R7 version — proven)
// ---------------------------------------------------------------------------
__global__ __launch_bounds__(256) void k1_proj(
    const void* __restrict__ Xv, const void* __restrict__ Wv,
    const void* __restrict__ a1v_, const void* __restrict__ a2v_,
    ushort* __restrict__ HtT, float* __restrict__ s1, float* __restrict__ s2,
    const int* __restrict__ flagp)
{
  const int is_bf16 = *flagp;
  const int wave = threadIdx.x >> 6;
  const int lane = threadIdx.x & 63;
  const int i0 = blockIdx.x * 64 + wave * 16;
  const int col = lane & 15;
  const int q   = lane >> 4;

  short8 bfrag[4][4];
  float a1f[4], a2f[4];
  if (is_bf16) {
    const ushort* W = (const ushort*)Wv;
#pragma unroll
    for (int nt = 0; nt < 4; ++nt)
#pragma unroll
      for (int kc = 0; kc < 4; ++kc) {
        short8 b;
#pragma unroll
        for (int j = 0; j < 8; ++j)
          b[j] = (short)W[(kc*32 + q*8 + j)*FOUT + nt*16 + col];
        bfrag[nt][kc] = b;
      }
#pragma unroll
    for (int nt = 0; nt < 4; ++nt) {
      a1f[nt] = bf2f(((const ushort*)a1v_)[nt*16 + col]);
      a2f[nt] = bf2f(((const ushort*)a2v_)[nt*16 + col]);
    }
  } else {
    const float* W = (const float*)Wv;
#pragma unroll
    for (int nt = 0; nt < 4; ++nt)
#pragma unroll
      for (int kc = 0; kc < 4; ++kc) {
        short8 b;
#pragma unroll
        for (int j = 0; j < 8; ++j)
          b[j] = (short)f2bf_u(W[(kc*32 + q*8 + j)*FOUT + nt*16 + col]);
        bfrag[nt][kc] = b;
      }
#pragma unroll
    for (int nt = 0; nt < 4; ++nt) {
      a1f[nt] = ((const float*)a1v_)[nt*16 + col];
      a2f[nt] = ((const float*)a2v_)[nt*16 + col];
    }
  }

  floatx4 acc[4] = {{0.f,0.f,0.f,0.f},{0.f,0.f,0.f,0.f},
                    {0.f,0.f,0.f,0.f},{0.f,0.f,0.f,0.f}};
#pragma unroll
  for (int kc = 0; kc < 4; ++kc) {
    short8 a;
    if (is_bf16) {
      a = *(const short8*)&((const ushort*)Xv)[(size_t)(i0 + col)*FIN + kc*32 + q*8];
    } else {
      const float* X = (const float*)Xv;
      float4 x0 = *(const float4*)&X[(size_t)(i0 + col)*FIN + kc*32 + q*8];
      float4 x1 = *(const float4*)&X[(size_t)(i0 + col)*FIN + kc*32 + q*8 + 4];
      a[0] = (short)f2bf_u(x0.x); a[1] = (short)f2bf_u(x0.y);
      a[2] = (short)f2bf_u(x0.z); a[3] = (short)f2bf_u(x0.w);
      a[4] = (short)f2bf_u(x1.x); a[5] = (short)f2bf_u(x1.y);
      a[6] = (short)f2bf_u(x1.z); a[7] = (short)f2bf_u(x1.w);
    }
#pragma unroll
    for (int nt = 0; nt < 4; ++nt)
      acc[nt] = __builtin_amdgcn_mfma_f32_16x16x32_bf16(a, bfrag[nt][kc], acc[nt], 0, 0, 0);
  }

  float s1p[4] = {0,0,0,0}, s2p[4] = {0,0,0,0};
#pragma unroll
  for (int nt = 0; nt < 4; ++nt) {
    ushort4 pk;
    pk.x = (ushort)f2bf_u(acc[nt][0]);
    pk.y = (ushort)f2bf_u(acc[nt][1]);
    pk.z = (ushort)f2bf_u(acc[nt][2]);
    pk.w = (ushort)f2bf_u(acc[nt][3]);
    *(ushort4*)&HtT[(size_t)(nt*16 + col)*NV + i0 + q*4] = pk;
#pragma unroll
    for (int reg = 0; reg < 4; ++reg) {
      s1p[reg] += acc[nt][reg] * a1f[nt];
      s2p[reg] += acc[nt][reg] * a2f[nt];
    }
  }
#pragma unroll
  for (int m = 1; m < 16; m <<= 1)
#pragma unroll
    for (int reg = 0; reg < 4; ++reg) {
      s1p[reg] += __shfl_xor(s1p[reg], m, 64);
      s2p[reg] += __shfl_xor(s2p[reg], m, 64);
    }
  if (col == 0)
#pragma unroll
    for (int reg = 0; reg < 4; ++reg) {
      s1[i0 + q*4 + reg] = s1p[reg];
      s2[i0 + q*4 + reg] = s2p[reg];
    }
}

// ---------------------------------------------------------------------------
// Kernel 2 (R7 staged loop, MT=32 rows/block, 2 column slices):
// halves per-A-byte Ht staging traffic + barrier events vs R7; B-fragment
// ds_reads reused across the two M-tiles. grid = 2 x 256 = 512 blocks.
// ---------------------------------------------------------------------------
#define CT 128
#define SLICES 2
#define SW (NV / SLICES)   // 4096
#define NTL (SW / CT)      // 32 tiles per sweep
#define PST 136            // 128+8 bf16; 272 B row stride, uniform banks

__global__ __launch_bounds__(256, 4) void k2_attn(
    const int* __restrict__ A, const ushort* __restrict__ HtT,
    const float* __restrict__ s1g, const float* __restrict__ s2g,
    float* __restrict__ Part, float* __restrict__ Lpart)
{
  __shared__ __align__(16) ushort Pl[32 * PST];   //  8.7 KB (32 P rows)
  __shared__ __align__(16) ushort Hl[64 * PST];   // 17.4 KB
  __shared__ float Lrow[32];

  const int tid  = threadIdx.x;
  const int wave = tid >> 6;
  const int lane = tid & 63;
  const int sl   = blockIdx.x & (SLICES - 1);
  const int rb   = blockIdx.x >> 1;
  const int i0   = rb * 32;
  const int q    = lane >> 4;
  const int mcol = lane & 15;
  const int r    = tid >> 4;        // 0..15; this thread also handles r+16
  const int cb   = (tid & 15) * 8;  // col offset in tile (8 cols/thread)
  const int c0s  = sl * SW;
  const int t0   = (rb * 23) & (NTL - 1);   // column-phase stagger

  const float s1a = s1g[i0 + r];
  const float s1b = s1g[i0 + r + 16];
  const size_t abaseA = (size_t)(i0 + r) * NV + c0s + cb;
  const size_t abaseB = (size_t)(i0 + r + 16) * NV + c0s + cb;

  float LpA = 0.f, LpB = 0.f;
  floatx4 acc0 = {0.f,0.f,0.f,0.f};   // C rows 0-15
  floatx4 acc1 = {0.f,0.f,0.f,0.f};   // C rows 16-31

  // ---- prefetch first tile (phase t0) ----
  int4 avA0, avA1, avB0, avB1;
  float4 sv0, sv1;
  short8 hv[4];
  {
    const int c = t0 * CT;
    avA0 = *(const int4*)&A[abaseA + c];
    avA1 = *(const int4*)&A[abaseA + c + 4];
    avB0 = *(const int4*)&A[abaseB + c];
    avB1 = *(const int4*)&A[abaseB + c + 4];
    sv0 = *(const float4*)&s2g[c0s + c + cb];
    sv1 = *(const float4*)&s2g[c0s + c + cb + 4];
#pragma unroll
    for (int it = 0; it < 4; ++it)
      hv[it] = *(const short8*)&HtT[(size_t)(r + 16*it) * NV + c0s + c + cb];
  }

  for (int t = 0; t < NTL; ++t) {
    __syncthreads();   // Pl/Hl free (prev MFMA done)

    // ---- stage: exp + pack P (rows r and r+16), copy Ht tile ----
    {
      float x0 = s1a + sv0.x, x1 = s1a + sv0.y, x2 = s1a + sv0.z, x3 = s1a + sv0.w;
      float x4 = s1a + sv1.x, x5 = s1a + sv1.y, x6 = s1a + sv1.z, x7 = s1a + sv1.w;
      float w0 = avA0.x ? __expf(fmaxf(x0, 0.2f*x0)) : 0.f;
      float w1 = avA0.y ? __expf(fmaxf(x1, 0.2f*x1)) : 0.f;
      float w2 = avA0.z ? __expf(fmaxf(x2, 0.2f*x2)) : 0.f;
      float w3 = avA0.w ? __expf(fmaxf(x3, 0.2f*x3)) : 0.f;
      float w4 = avA1.x ? __expf(fmaxf(x4, 0.2f*x4)) : 0.f;
      float w5 = avA1.y ? __expf(fmaxf(x5, 0.2f*x5)) : 0.f;
      float w6 = avA1.z ? __expf(fmaxf(x6, 0.2f*x6)) : 0.f;
      float w7 = avA1.w ? __expf(fmaxf(x7, 0.2f*x7)) : 0.f;
      LpA += ((w0 + w1) + (w2 + w3)) + ((w4 + w5) + (w6 + w7));
      uint4 pk;
      pk.x = f2bf_u(w0) | (f2bf_u(w1) << 16);
      pk.y = f2bf_u(w2) | (f2bf_u(w3) << 16);
      pk.z = f2bf_u(w4) | (f2bf_u(w5) << 16);
      pk.w = f2bf_u(w6) | (f2bf_u(w7) << 16);
      *(uint4*)&Pl[r * PST + cb] = pk;

      float y0 = s1b + sv0.x, y1 = s1b + sv0.y, y2 = s1b + sv0.z, y3 = s1b + sv0.w;
      float y4 = s1b + sv1.x, y5 = s1b + sv1.y, y6 = s1b + sv1.z, y7 = s1b + sv1.w;
      float v0 = avB0.x ? __expf(fmaxf(y0, 0.2f*y0)) : 0.f;
      float v1 = avB0.y ? __expf(fmaxf(y1, 0.2f*y1)) : 0.f;
      float v2 = avB0.z ? __expf(fmaxf(y2, 0.2f*y2)) : 0.f;
      float v3 = avB0.w ? __expf(fmaxf(y3, 0.2f*y3)) : 0.f;
      float v4 = avB1.x ? __expf(fmaxf(y4, 0.2f*y4)) : 0.f;
      float v5 = avB1.y ? __expf(fmaxf(y5, 0.2f*y5)) : 0.f;
      float v6 = avB1.z ? __expf(fmaxf(y6, 0.2f*y6)) : 0.f;
      float v7 = avB1.w ? __expf(fmaxf(y7, 0.2f*y7)) : 0.f;
      LpB += ((v0 + v1) + (v2 + v3)) + ((v4 + v5) + (v6 + v7));
      uint4 pk2;
      pk2.x = f2bf_u(v0) | (f2bf_u(v1) << 16);
      pk2.y = f2bf_u(v2) | (f2bf_u(v3) << 16);
      pk2.z = f2bf_u(v4) | (f2bf_u(v5) << 16);
      pk2.w = f2bf_u(v6) | (f2bf_u(v7) << 16);
      *(uint4*)&Pl[(r + 16) * PST + cb] = pk2;

#pragma unroll
      for (int it = 0; it < 4; ++it)
        *(short8*)&Hl[(r + 16*it) * PST + cb] = hv[it];
    }

    __syncthreads();   // publish

    // ---- prefetch next tile (flies across the MFMA phase) ----
    if (t + 1 < NTL) {
      const int c2 = ((t + 1 + t0) & (NTL - 1)) * CT;
      avA0 = *(const int4*)&A[abaseA + c2];
      avA1 = *(const int4*)&A[abaseA + c2 + 4];
      avB0 = *(const int4*)&A[abaseB + c2];
      avB1 = *(const int4*)&A[abaseB + c2 + 4];
      sv0 = *(const float4*)&s2g[c0s + c2 + cb];
      sv1 = *(const float4*)&s2g[c0s + c2 + cb + 4];
#pragma unroll
      for (int it = 0; it < 4; ++it)
        hv[it] = *(const short8*)&HtT[(size_t)(r + 16*it) * NV + c0s + c2 + cb];
    }

    // ---- MFMA: B-frag reused across the 2 M-tiles ----
#pragma unroll
    for (int kc = 0; kc < 4; ++kc) {
      short8 bf = *(const short8*)&Hl[(wave*16 + mcol) * PST + kc*32 + q*8];
      short8 af0 = *(const short8*)&Pl[mcol * PST + kc*32 + q*8];
      short8 af1 = *(const short8*)&Pl[(16 + mcol) * PST + kc*32 + q*8];
      acc0 = __builtin_amdgcn_mfma_f32_16x16x32_bf16(af0, bf, acc0, 0, 0, 0);
      acc1 = __builtin_amdgcn_mfma_f32_16x16x32_bf16(af1, bf, acc1, 0, 0, 0);
    }
  }

  // ---- denominators: reduce over the 16 lanes sharing row r ----
#pragma unroll
  for (int m = 1; m < 16; m <<= 1) {
    LpA += __shfl_xor(LpA, m, 64);
    LpB += __shfl_xor(LpB, m, 64);
  }
  if (mcol == 0) { Lrow[r] = LpA; Lrow[r + 16] = LpB; }
  __syncthreads();

  // ---- per-slice partials (C/D: col=mcol, row=q*4+reg) ----
#pragma unroll
  for (int reg = 0; reg < 4; ++reg) {
    int r0 = q*4 + reg;
    Part[((size_t)sl * NV + i0 + r0) * FOUT + wave*16 + mcol] = acc0[reg];
    Part[((size_t)sl * NV + i0 + 16 + r0) * FOUT + wave*16 + mcol] = acc1[reg];
  }
  if (tid < 32 && lane < 32) { /* no-op guard */ }
  if (mcol == 0 && wave == 0) {
    // one thread per q writes nothing extra; Lpart written below by 32 threads
  }
  if (tid < 32) Lpart[(size_t)sl * NV + i0 + tid] = Lrow[tid];
}

// ---------------------------------------------------------------------------
// Kernel 3: combine 2 slices, divide, store.
// ---------------------------------------------------------------------------
__global__ __launch_bounds__(256) void k3_combine(
    const float* __restrict__ Part, const float* __restrict__ Lpart,
    void* __restrict__ outv, const int* __restrict__ flagp)
{
  const int is_bf16 = *flagp;
  const int g   = blockIdx.x * 256 + threadIdx.x;
  const int row = g >> 4;
  const int fb  = (g & 15) * 4;

  float4 s = {0.f, 0.f, 0.f, 0.f};
  float L = 0.f;
#pragma unroll
  for (int sl = 0; sl < SLICES; ++sl) {
    float4 v = *(const float4*)&Part[((size_t)sl * NV + row) * FOUT + fb];
    s.x += v.x; s.y += v.y; s.z += v.z; s.w += v.w;
    L += Lpart[(size_t)sl * NV + row];
  }
  const float inv = __frcp_rn(L);
  s.x *= inv; s.y *= inv; s.z *= inv; s.w *= inv;
  if (is_bf16) {
    ushort4 pk;
    pk.x = (ushort)f2bf_u(s.x); pk.y = (ushort)f2bf_u(s.y);
    pk.z = (ushort)f2bf_u(s.z); pk.w = (ushort)f2bf_u(s.w);
    *(ushort4*)&((ushort*)outv)[(size_t)row * FOUT + fb] = pk;
  } else {
    *(float4*)&((float*)outv)[(size_t)row * FOUT + fb] = s;
  }
}

extern "C" void kernel_launch(void* const* d_in, const int* in_sizes, int n_in,
                              void* d_out, int out_size, void* d_ws, size_t ws_size,
                              hipStream_t stream) {
  const void* X  = d_in[0];                 // f32 (or bf16) [8192][128]
  const int*  A  = (const int*)d_in[1];     // int32 [8192][8192]
  const void* W  = d_in[2];                 // f32 (or bf16) [128][64]
  const void* a1 = d_in[3];                 // f32 (or bf16) [64]
  const void* a2 = d_in[4];                 // f32 (or bf16) [64]

  char* ws = (char*)d_ws;
  ushort* HtT   = (ushort*)ws;                         // 1 MiB
  float*  s1    = (float*)(ws + (size_t)FOUT*NV*2);    // 32 KiB
  float*  s2    = s1 + NV;                             // 32 KiB
  int*    flag  = (int*)(s2 + NV);                     // 16 B (padded)
  float*  Part  = (float*)((char*)flag + 16);          // 2*8192*64*4 = 4 MiB
  float*  Lpart = Part + (size_t)SLICES * NV * FOUT;   // 64 KiB

  hipLaunchKernelGGL(k0_detect, dim3(1), dim3(64), 0, stream,
                     (const uint*)X, flag);
  hipLaunchKernelGGL(k1_proj, dim3(NV/64), dim3(256), 0, stream,
                     X, W, a1, a2, HtT, s1, s2, flag);
  hipLaunchKernelGGL(k2_attn, dim3((NV/32) * SLICES), dim3(256), 0, stream,
                     A, HtT, s1, s2, Part, Lpart);
  hipLaunchKernelGGL(k3_combine, dim3(NV*FOUT/4/256), dim3(256), 0, stream,
                     Part, Lpart, d_out, flag);
}